// Round 5
// baseline (321.769 us; speedup 1.0000x reference)
//
#include <hip/hip_runtime.h>

#define HH 96
#define WW 96
#define CC 21
#define BB 2
#define NN (HH*WW)          // 9216
#define NT16 (NN/16)        // 576 sorted 16-tiles per batch
#define NJB  (NN/32)        // 288 j-blocks per batch
#define NCONV (BB*CC)       // 42 conv planes (blocks 0..41 of iter kernel)
#define NBLK  576           // iter-kernel blocks; block does tiles {bid, bid+576}
#define PRUNE_T 20.0f       // exp2-domain skip threshold (mass <= N*2^-20)
#define GST 104             // LDS row stride for 96-wide bf16 rows

// feature pre-scale folds 1/2 and log2(e): k = exp2(-sum(diff^2))
#define KSA2 (0.84932184f / 160.0f)   // bilateral spatial
#define KSB2 (0.84932184f / 3.0f)     // bilateral color
#define GL2  (1.44269504f / 18.0f)    // spatial kernel exp(-d^2/18) in exp2 units

typedef __attribute__((ext_vector_type(4))) float f32x4;
typedef __attribute__((ext_vector_type(8))) short short8;
typedef __attribute__((ext_vector_type(4))) int int4v;

static __device__ inline unsigned pk_bf16(float a, float b) {
    unsigned ua = __builtin_bit_cast(unsigned, a);
    unsigned ub = __builtin_bit_cast(unsigned, b);
    ua += 0x7FFF + ((ua >> 16) & 1);
    ub += 0x7FFF + ((ub >> 16) & 1);
    return (ua >> 16) | (ub & 0xFFFF0000u);
}
static __device__ inline unsigned short bf16_1(float a) {
    unsigned ua = __builtin_bit_cast(unsigned, a);
    ua += 0x7FFF + ((ua >> 16) & 1);
    return (unsigned short)(ua >> 16);
}

// ===== D1: hist + tables + smht const rows (BOTH buffers) + BND + flags ====
__global__ __launch_bounds__(256) void histprep_kernel(
    const float* __restrict__ rgb, unsigned* __restrict__ gha,
    unsigned* __restrict__ ghb, float* __restrict__ sxt,
    unsigned short* __restrict__ gbt, unsigned short* __restrict__ smht0,
    unsigned short* __restrict__ smht1, unsigned* __restrict__ bnd,
    unsigned* __restrict__ cflag)
{
    int tid = threadIdx.x;
    int gid = blockIdx.x * 256 + tid;
    if (gid < BB * NN) {
        int b = gid / NN;
        const float* rp = rgb + (size_t)gid * 3;
        int cr = min(15, (int)rp[0] >> 4);
        int cg = min(15, (int)rp[1] >> 4);
        int cb = min(15, (int)rp[2] >> 4);
        int cell = b * 4096 + ((cr << 8) | (cg << 4) | cb);
        atomicAdd(&gha[cell], 1u);
        atomicAdd(&ghb[cell], 1u);
    }
    unsigned* s0 = (unsigned*)smht0;
    unsigned* s1 = (unsigned*)smht1;
    for (int o = gid; o < BB * 11 * (NN / 2); o += 104 * 256) {
        int b = o / (11 * (NN / 2));
        int rem = o - b * 11 * (NN / 2);
        int rr = rem / (NN / 2), col = rem - rr * (NN / 2);
        unsigned v = (rr == 0) ? 0x3F803F80u : 0u;
        size_t off = (size_t)(b * 32 + 21 + rr) * (NN / 2) + col;
        s0[off] = v; s1[off] = v;
    }
    if (gid < BB * NT16 * 3) {
        int t2 = gid / 3, f = gid - t2 * 3;
        bnd[t2 * 6 + 2 * f]     = 0x7F7FFFFFu;   // lo = +FLT_MAX bits (poison-proof)
        bnd[t2 * 6 + 2 * f + 1] = 0u;            // hi = 0 (features >= 0)
    }
    if (gid < 16) cflag[gid] = 0u;               // producer flags (it*2 + b)
    if (blockIdx.x == 0) {
        __shared__ float gt[96];
        if (tid < 96) gt[tid] = __builtin_amdgcn_exp2f(-(float)(tid * tid) * GL2);
        __syncthreads();
        if (tid < 96) {
            float s = 0.f;
            for (int v = 0; v < 96; v++) s += gt[abs(tid - v)];
            sxt[tid] = s;
            for (int v = 0; v < 96; v++) gbt[tid * 96 + v] = bf16_1(gt[abs(tid - v)]);
        }
    }
}

// ===== D2: fused scan + scatter + bbox + sinv + iteration-0 softmax ========
__global__ __launch_bounds__(256) void scanscatter_kernel(
    const float* __restrict__ rgb, const unsigned* __restrict__ gha,
    unsigned* __restrict__ ghb, const unsigned* __restrict__ sent,
    int* __restrict__ sinv, float* __restrict__ fjs, unsigned* __restrict__ bnd,
    const float* __restrict__ q, unsigned short* __restrict__ smpb,
    unsigned short* __restrict__ smht)
{
    __shared__ int sOff[4096];
    __shared__ int ps[256];
    unsigned sv = sent[0];
    int t = threadIdx.x;
    int blk = blockIdx.x;
    int b = blk / (36);                       // 36 blocks per batch
    int base = b * 4096 + t * 16;
    int loc[16], s = 0;
#pragma unroll
    for (int k = 0; k < 16; k++) { loc[k] = (int)(gha[base + k] - sv); s += loc[k]; }
    ps[t] = s;
    __syncthreads();
    for (int off = 1; off < 256; off <<= 1) {
        int add = (t >= off) ? ps[t - off] : 0;
        __syncthreads();
        ps[t] += add;
        __syncthreads();
    }
    int run = ps[t] - s;
#pragma unroll
    for (int k = 0; k < 16; k++) { sOff[t * 16 + k] = run; run += loc[k]; }
    __syncthreads();
    int idx = blk * 256 + t;                  // global pixel, == b*NN + p
    int p = idx - b * NN;
    const float* rp = rgb + (size_t)idx * 3;
    float r = rp[0], g = rp[1], bl = rp[2];
    int cr = min(15, (int)r >> 4);
    int cg = min(15, (int)g >> 4);
    int cb = min(15, (int)bl >> 4);
    int cell = (cr << 8) | (cg << 4) | cb;
    unsigned old = atomicSub(&ghb[b * 4096 + cell], 1u);
    int pos = sOff[cell] + (int)(old - sv) - 1;
    sinv[b * NN + pos] = p;                   // inverse permutation (sorted -> pixel)
    int y = p / WW, x = p - y * WW;
    float fr = r * KSB2, fg = g * KSB2, fb2 = bl * KSB2;
    float* fb = fjs + (size_t)b * 5 * NN;
    fb[0 * NN + pos] = fr;
    fb[1 * NN + pos] = fg;
    fb[2 * NN + pos] = fb2;
    fb[3 * NN + pos] = (float)y * KSA2;
    fb[4 * NN + pos] = (float)x * KSA2;
    unsigned* bq = bnd + (size_t)(b * NT16 + (pos >> 4)) * 6;
    atomicMin(&bq[0], __float_as_uint(fr));  atomicMax(&bq[1], __float_as_uint(fr));
    atomicMin(&bq[2], __float_as_uint(fg));  atomicMax(&bq[3], __float_as_uint(fg));
    atomicMin(&bq[4], __float_as_uint(fb2)); atomicMax(&bq[5], __float_as_uint(fb2));
    const float* qp = q + (size_t)idx * CC;
    float v[CC], mx = -1e30f;
#pragma unroll
    for (int c = 0; c < CC; c++) { v[c] = qp[c]; mx = fmaxf(mx, v[c]); }
    float ssum = 0.f;
#pragma unroll
    for (int c = 0; c < CC; c++) { v[c] = __expf(v[c] - mx); ssum += v[c]; }
    float inv = 1.0f / ssum;
#pragma unroll
    for (int c = 0; c < CC; c++) {
        unsigned short h = bf16_1(v[c] * inv);
        smpb[(size_t)(b * CC + c) * NN + p] = h;
        smht[(size_t)(b * 32 + c) * NN + pos] = h;
    }
}

// ---------------- bilateral helpers (depth-2 pipelined j-set) --------------
struct JSet { float vf[5][8]; short8 sb0, sb1; };

static __device__ __forceinline__ void load_jset(
    JSet& s, const float* __restrict__ fb, const unsigned short* __restrict__ smb,
    int jb, int quad, int l16)
{
    int coff = jb * 32 + quad * 8;
#pragma unroll
    for (int f = 0; f < 5; f++) {
        const float4* pf = (const float4*)(fb + (size_t)f * NN + coff);
        float4 lo = pf[0], hi = pf[1];
        s.vf[f][0] = lo.x; s.vf[f][1] = lo.y; s.vf[f][2] = lo.z; s.vf[f][3] = lo.w;
        s.vf[f][4] = hi.x; s.vf[f][5] = hi.y; s.vf[f][6] = hi.z; s.vf[f][7] = hi.w;
    }
    s.sb0 = *(const short8*)(smb + (size_t)l16 * NN + coff);
    s.sb1 = *(const short8*)(smb + (size_t)(16 + l16) * NN + coff);
}

static __device__ __forceinline__ void compute_jset(
    const JSet& s, float fi0, float fi1, float fi2, float fi3, float fi4,
    f32x4& acc0, f32x4& acc1)
{
    float kf[8];
#pragma unroll
    for (int e = 0; e < 8; e++) {
        float d0 = s.vf[0][e] - fi0;
        float d1 = s.vf[1][e] - fi1;
        float d2 = s.vf[2][e] - fi2;
        float d3 = s.vf[3][e] - fi3;
        float d4 = s.vf[4][e] - fi4;
        float sm = d0 * d0;
        sm = fmaf(d1, d1, sm);
        sm = fmaf(d2, d2, sm);
        sm = fmaf(d3, d3, sm);
        sm = fmaf(d4, d4, sm);
        kf[e] = __builtin_amdgcn_exp2f(-sm);
    }
    int4v ap = { (int)pk_bf16(kf[0], kf[1]), (int)pk_bf16(kf[2], kf[3]),
                 (int)pk_bf16(kf[4], kf[5]), (int)pk_bf16(kf[6], kf[7]) };
    short8 afrag = __builtin_bit_cast(short8, ap);
    acc0 = __builtin_amdgcn_mfma_f32_16x16x32_bf16(afrag, s.sb0, acc0, 0, 0, 0);
    acc1 = __builtin_amdgcn_mfma_f32_16x16x32_bf16(afrag, s.sb1, acc1, 0, 0, 0);
}

// ===== K2: one kernel per CRF iteration =====================================
// 576 blocks, all co-resident (launch_bounds(256,4) -> >=4 blocks/CU -> 1024
// slots >= 576, so the flag wait cannot deadlock regardless of dispatch order).
// Blocks 0..41: spatial conv plane first, then RELEASE-add a per-(it,batch)
// flag (after conv finished READING smpb -> update may overwrite smpb safely).
// All blocks: 2 tiles (t=0: batch 0, t=1: batch 1): mask -> bilateral ->
// LDS-combine -> wait flag==21 (ACQUIRE invalidates L2 so spf from other XCDs
// is visible) -> fused norm+message+update+softmax for the tile's 16 pixels.
// smht is double-buffered across iterations (bil reads parity it, update
// writes parity it+1) to avoid read/write races without a grid barrier.
__global__ __launch_bounds__(256, 4) void conv_bil_upd_kernel(
    unsigned short* smpb, const unsigned short* __restrict__ gbt,
    const float* __restrict__ sxt, float* __restrict__ spf,
    const unsigned short* __restrict__ smht_r, unsigned short* __restrict__ smht_w,
    const float* __restrict__ fjs, const unsigned* __restrict__ bnd,
    const int* __restrict__ sinv, const float* __restrict__ u,
    const float* __restrict__ Ws, const float* __restrict__ Wb,
    const float* __restrict__ Mmat, float* __restrict__ qout,
    unsigned* cflag, int it, int wr)
{
    __shared__ __align__(16) char sh[19968];
    int tid = threadIdx.x;
    int lane = tid & 63, w = tid >> 6;
    int quad = lane >> 4, l16 = lane & 15;
    int bid = blockIdx.x;

    if (bid < NCONV) {
        // ---- conv role: plane (b,c) = bid ----
        unsigned short* C1t = (unsigned short*)sh;
        const unsigned short* plane = smpb + (size_t)bid * NN;
        for (int mt = w; mt < 6; mt += 4) {
            int m0 = mt * 16;
            short8 a[3];
#pragma unroll
            for (int kk = 0; kk < 3; kk++)
                a[kk] = *(const short8*)(plane + (size_t)(m0 + l16) * 96 + kk * 32 + quad * 8);
            f32x4 acc[6];
#pragma unroll
            for (int nt = 0; nt < 6; nt++) acc[nt] = (f32x4){0.f, 0.f, 0.f, 0.f};
#pragma unroll
            for (int nt = 0; nt < 6; nt++) {
#pragma unroll
                for (int kk = 0; kk < 3; kk++) {
                    short8 bf = *(const short8*)(gbt + (nt * 16 + l16) * 96 + kk * 32 + quad * 8);
                    acc[nt] = __builtin_amdgcn_mfma_f32_16x16x32_bf16(a[kk], bf, acc[nt], 0, 0, 0);
                }
            }
#pragma unroll
            for (int nt = 0; nt < 6; nt++) {
                unsigned* dst = (unsigned*)&C1t[(nt * 16 + l16) * GST + m0 + quad * 4];
                dst[0] = pk_bf16(acc[nt][0], acc[nt][1]);
                dst[1] = pk_bf16(acc[nt][2], acc[nt][3]);
            }
        }
        __syncthreads();
        float* outp = spf + (size_t)bid * NN;
        for (int mt = w; mt < 6; mt += 4) {
            int m0 = mt * 16;
            short8 a[3];
#pragma unroll
            for (int kk = 0; kk < 3; kk++)
                a[kk] = *(const short8*)(gbt + (m0 + l16) * 96 + kk * 32 + quad * 8);
            f32x4 acc[6];
#pragma unroll
            for (int nt = 0; nt < 6; nt++) acc[nt] = (f32x4){0.f, 0.f, 0.f, 0.f};
#pragma unroll
            for (int nt = 0; nt < 6; nt++) {
#pragma unroll
                for (int kk = 0; kk < 3; kk++) {
                    short8 bf = *(const short8*)&C1t[(nt * 16 + l16) * GST + kk * 32 + quad * 8];
                    acc[nt] = __builtin_amdgcn_mfma_f32_16x16x32_bf16(a[kk], bf, acc[nt], 0, 0, 0);
                }
            }
#pragma unroll
            for (int nt = 0; nt < 6; nt++) {
                int x = nt * 16 + l16;
                float sx = sxt[x];
#pragma unroll
                for (int r = 0; r < 4; r++) {
                    int y = m0 + quad * 4 + r;
                    float invn = __builtin_amdgcn_rcpf(sxt[y] * sx);
                    outp[y * 96 + x] = acc[nt][r] * invn;
                }
            }
        }
        __syncthreads();   // all stores drained (vmcnt(0) before barrier)
        if (tid == 0)
            __hip_atomic_fetch_add(&cflag[it * 2 + bid / CC], 1u,
                                   __ATOMIC_RELEASE, __HIP_MEMORY_SCOPE_AGENT);
        __syncthreads();   // protect LDS reuse below
    }

    // ---- LDS layout for bilateral+update (fits under conv's 19968 C1t) ----
    unsigned short* jl = (unsigned short*)sh;          // [0,576)
    float* cbuf  = (float*)(sh + 640);                 // 4*384 floats
    float* sW    = (float*)(sh + 6784);                // 3*441 floats
    int*   sinvp = (int*)(sh + 12080);                 // 16
    float* ninvb = (float*)(sh + 12144);               // 16
    float* spvb  = (float*)(sh + 12208);               // 336
    float* blvb  = (float*)(sh + 13552);               // 336
    float* msgb  = (float*)(sh + 14896);               // 336
    float* qvb   = (float*)(sh + 16240);               // 336

    for (int t2 = tid; t2 < 441; t2 += 256) {
        sW[t2] = Ws[t2]; sW[441 + t2] = Wb[t2]; sW[882 + t2] = Mmat[t2];
    }

    for (int tt = 0; tt < 2; ++tt) {
        int bt = bid + tt * NBLK;             // t=0: batch 0 tiles, t=1: batch 1
        int b = bt / NT16, tile16 = bt - b * NT16;
        __syncthreads();                      // LDS reuse across tt / after sW

        // mask: keep-list for this tile (all 4 waves redundantly, identical)
        const float* bndf = (const float*)bnd;
        const float* tb = bndf + (size_t)bt * 6;
        float tlo0 = tb[0], thi0 = tb[1], tlo1 = tb[2], thi1 = tb[3], tlo2 = tb[4], thi2 = tb[5];
        const float* bb = bndf + (size_t)b * NT16 * 6;
        int n = 0;
#pragma unroll
        for (int r = 0; r < 5; r++) {
            int jb = r * 64 + lane;
            bool keep = false;
            if (jb < NJB) {
                const float* a0 = bb + (size_t)(2 * jb) * 6;
                float s = 0.f;
#pragma unroll
                for (int f = 0; f < 3; f++) {
                    float jlo = fminf(a0[2 * f], a0[6 + 2 * f]);
                    float jhi = fmaxf(a0[2 * f + 1], a0[6 + 2 * f + 1]);
                    float lo = (f == 0) ? tlo0 : (f == 1) ? tlo1 : tlo2;
                    float hi = (f == 0) ? thi0 : (f == 1) ? thi1 : thi2;
                    float gap = fmaxf(0.f, fmaxf(lo - jhi, jlo - hi));
                    s = fmaf(gap, gap, s);
                }
                keep = (s <= PRUNE_T);
            }
            unsigned long long m = __ballot(keep);
            if (keep) {
                int pre = __popcll(m & ((1ull << lane) - 1ull));
                jl[n + pre] = (unsigned short)jb;
            }
            n += __popcll(m);
        }
        __syncthreads();

        // bilateral: 4 waves split keep-list stride-4
        int i = tile16 * 16 + l16;
        const float* fb = fjs + (size_t)b * 5 * NN;
        float fi0 = fb[0 * NN + i], fi1 = fb[1 * NN + i], fi2 = fb[2 * NN + i];
        float fi3 = fb[3 * NN + i], fi4 = fb[4 * NN + i];
        f32x4 acc0 = {0.f, 0.f, 0.f, 0.f};
        f32x4 acc1 = {0.f, 0.f, 0.f, 0.f};
        const unsigned short* smb = smht_r + (size_t)b * 32 * NN;
        int k = w;
        if (k < n) {
            JSet A, B;
            load_jset(A, fb, smb, jl[k], quad, l16);
            while (true) {
                int kn = k + 4;
                load_jset(B, fb, smb, jl[kn < n ? kn : k], quad, l16);
                compute_jset(A, fi0, fi1, fi2, fi3, fi4, acc0, acc1);
                k = kn;
                if (k >= n) break;
                kn = k + 4;
                load_jset(A, fb, smb, jl[kn < n ? kn : k], quad, l16);
                compute_jset(B, fi0, fi1, fi2, fi3, fi4, acc0, acc1);
                k = kn;
                if (k >= n) break;
            }
        }
#pragma unroll
        for (int r = 0; r < 4; r++)
            cbuf[w * 384 + (quad * 4 + r) * 24 + l16] = acc0[r];
        if (l16 < 6) {
#pragma unroll
            for (int r = 0; r < 4; r++)
                cbuf[w * 384 + (quad * 4 + r) * 24 + 16 + l16] = acc1[r];
        }
        __syncthreads();

        // pre-wait prep: pixel map + norm
        if (tid < 16) {
            sinvp[tid] = sinv[b * NN + tile16 * 16 + tid];
            float s4 = cbuf[tid * 24 + 21] + cbuf[384 + tid * 24 + 21]
                     + cbuf[768 + tid * 24 + 21] + cbuf[1152 + tid * 24 + 21];
            ninvb[tid] = 1.0f / s4;
        }
        __syncthreads();
        for (int e = tid; e < 16 * CC; e += 256) {
            int r = e / CC, c = e - r * CC;
            float s4 = cbuf[r * 24 + c] + cbuf[384 + r * 24 + c]
                     + cbuf[768 + r * 24 + c] + cbuf[1152 + r * 24 + c];
            blvb[e] = s4 * ninvb[r];
        }

        // wait for this batch's 21 conv planes (RELEASE'd after writing spf)
        if (tid == 0) {
            while (__hip_atomic_load(&cflag[it * 2 + b], __ATOMIC_RELAXED,
                                     __HIP_MEMORY_SCOPE_AGENT) < (unsigned)CC)
                __builtin_amdgcn_s_sleep(2);
            (void)__hip_atomic_load(&cflag[it * 2 + b], __ATOMIC_ACQUIRE,
                                    __HIP_MEMORY_SCOPE_AGENT);
        }
        __syncthreads();

        // gather conv results for the 16 pixels
        for (int e = tid; e < 16 * CC; e += 256) {
            int r = e / CC, c = e - r * CC;
            spvb[e] = spf[(size_t)(b * CC + c) * NN + sinvp[r]];
        }
        __syncthreads();
        // messages
        for (int e = tid; e < 16 * CC; e += 256) {
            int r = e / CC, c = e - r * CC;
            float a = 0.f;
            const float* wr2 = &sW[c * CC];
            const float* br = &sW[441 + c * CC];
#pragma unroll
            for (int c2 = 0; c2 < CC; c2++) a = fmaf(wr2[c2], spvb[r * CC + c2], a);
#pragma unroll
            for (int c2 = 0; c2 < CC; c2++) a = fmaf(br[c2], blvb[r * CC + c2], a);
            msgb[e] = a;
        }
        __syncthreads();
        // compatibility + unary update
        for (int e = tid; e < 16 * CC; e += 256) {
            int r = e / CC, c = e - r * CC;
            int p = sinvp[r];
            float a = u[((size_t)b * NN + p) * CC + c];
            const float* mr = &sW[882 + c * CC];
#pragma unroll
            for (int c2 = 0; c2 < CC; c2++) a = fmaf(-mr[c2], msgb[r * CC + c2], a);
            if (wr) qvb[e] = a;
            else qout[((size_t)b * NN + p) * CC + c] = a;
        }
        if (wr) {
            __syncthreads();
            if (tid < 16) {
                int r = tid;
                float m = -1e30f;
#pragma unroll
                for (int c = 0; c < CC; c++) m = fmaxf(m, qvb[r * CC + c]);
                float ssum = 0.f;
                float ev[CC];
#pragma unroll
                for (int c = 0; c < CC; c++) { ev[c] = __expf(qvb[r * CC + c] - m); ssum += ev[c]; }
                float inv = 1.0f / ssum;
                int p = sinvp[r];
                int s = tile16 * 16 + r;
#pragma unroll
                for (int c = 0; c < CC; c++) {
                    unsigned short h = bf16_1(ev[c] * inv);
                    smpb[(size_t)(b * CC + c) * NN + p] = h;
                    smht_w[(size_t)(b * 32 + c) * NN + s] = h;
                }
            }
        }
    }
}

extern "C" void kernel_launch(void* const* d_in, const int* in_sizes, int n_in,
                              void* d_out, int out_size, void* d_ws, size_t ws_size,
                              hipStream_t stream)
{
    const float* unary = (const float*)d_in[0];  // [B,H,W,C]
    const float* rgb   = (const float*)d_in[1];  // [B,H,W,3]
    const float* Ws    = (const float*)d_in[2];
    const float* Wb    = (const float*)d_in[3];
    const float* M     = (const float*)d_in[4];
    float* out = (float*)d_out;                  // [B,N,C]

    float* SXT  = (float*)d_ws;                            // 96
    float* FJS  = SXT + 96;                                // B*5*N
    float* SPF  = FJS + (size_t)BB * 5 * NN;               // B*21*N
    unsigned* BND = (unsigned*)(SPF + (size_t)BB * CC * NN);   // B*576*6
    int*   SINV = (int*)(BND + (size_t)BB * NT16 * 6);     // B*N
    unsigned* GHA = (unsigned*)(SINV + BB * NN);           // B*4096 (poison-based)
    unsigned* GHB = GHA + BB * 4096;                       // B*4096 (poison-based)
    unsigned* CFLAG = GHB + BB * 4096;                     // 16 (zeroed in D1)
    unsigned* SENT = CFLAG + 16;                           // 1 (NEVER written)
    unsigned short* SMHT0 = (unsigned short*)(SENT + 1);   // B*32*N
    unsigned short* SMHT1 = SMHT0 + (size_t)BB * 32 * NN;  // B*32*N
    unsigned short* SMPB  = SMHT1 + (size_t)BB * 32 * NN;  // B*21*N
    unsigned short* GBT   = SMPB + (size_t)BB * CC * NN;   // 96*96

    histprep_kernel<<<104, 256, 0, stream>>>(rgb, GHA, GHB, SXT, GBT, SMHT0, SMHT1,
                                             BND, CFLAG);
    scanscatter_kernel<<<BB * 36, 256, 0, stream>>>(rgb, GHA, GHB, SENT, SINV,
                                                    FJS, BND, unary, SMPB, SMHT0);
    for (int it = 0; it < 5; ++it) {
        unsigned short* SR = (it & 1) ? SMHT1 : SMHT0;
        unsigned short* SW = (it & 1) ? SMHT0 : SMHT1;
        conv_bil_upd_kernel<<<NBLK, 256, 0, stream>>>(
            SMPB, GBT, SXT, SPF, SR, SW, FJS, BND, SINV, unary,
            Ws, Wb, M, out, CFLAG, it, (it < 4) ? 1 : 0);
    }
}